// Round 1
// baseline (998.837 us; speedup 1.0000x reference)
//
#include <hip/hip_runtime.h>
#include <cmath>

#define K_SEG 50
#define ITERS 10
#define H_IMG 512
#define W_IMG 512
#define NPIX (H_IMG * W_IMG)
#define BATCH 16
#define TPB 256
#define PPT 4

// ws layout:
//   gsums  : double[BATCH][K_SEG][6]   (r,g,b,fy,fx,count)   offset 0        (38400 B)
//   centers: float [BATCH][K_SEG][5]                          offset 38400    (16000 B)
//   c2s    : float [BATCH][K_SEG]                             offset 54400    (3200 B)

__global__ void init_kernel(const float* __restrict__ x, double* __restrict__ gsums,
                            float* __restrict__ centers, float* __restrict__ c2s,
                            float ratiof) {
    int b = blockIdx.x;
    int t = threadIdx.x;
    for (int i = t; i < K_SEG * 6; i += blockDim.x) gsums[b * K_SEG * 6 + i] = 0.0;
    if (t < K_SEG) {
        int i = t >> 3, j = t & 7;
        int y = 32 + 64 * i, xc = 32 + 64 * j;  // cy=(i+0.5)*512/8, cx likewise
        const float* xb = x + (size_t)b * 3 * NPIX;
        int p = y * W_IMG + xc;
        float r = xb[p], g = xb[NPIX + p], bl = xb[2 * NPIX + p];
        float fy = (float)y * ratiof, fx = (float)xc * ratiof;
        float* c = centers + (b * K_SEG + t) * 5;
        c[0] = r; c[1] = g; c[2] = bl; c[3] = fy; c[4] = fx;
        c2s[b * K_SEG + t] = (((r * r + g * g) + bl * bl) + fy * fy) + fx * fx;
    }
}

__global__ void __launch_bounds__(TPB) assign_kernel(
        const float* __restrict__ x, double* __restrict__ gsums,
        const float* __restrict__ centers, const float* __restrict__ c2s,
        float ratiof) {
    __shared__ float cen[K_SEG][5];
    __shared__ float c2l[K_SEG];
    __shared__ double part[K_SEG][6];
    int b = blockIdx.y;
    int t = threadIdx.x;

    const float* csrc = centers + b * K_SEG * 5;
    for (int i = t; i < K_SEG * 5; i += TPB) ((float*)cen)[i] = csrc[i];
    for (int i = t; i < K_SEG; i += TPB) c2l[i] = c2s[b * K_SEG + i];
    for (int i = t; i < K_SEG * 6; i += TPB) ((double*)part)[i] = 0.0;
    __syncthreads();

    int p0 = (blockIdx.x * TPB + t) * PPT;
    const float* xb = x + (size_t)b * 3 * NPIX;
    float4 r4 = *(const float4*)(xb + p0);
    float4 g4 = *(const float4*)(xb + NPIX + p0);
    float4 b4 = *(const float4*)(xb + 2 * NPIX + p0);
    int y = p0 >> 9;
    int xc = p0 & (W_IMG - 1);
    float fy = (float)y * ratiof;

    float rr[PPT] = {r4.x, r4.y, r4.z, r4.w};
    float gg[PPT] = {g4.x, g4.y, g4.z, g4.w};
    float bb[PPT] = {b4.x, b4.y, b4.z, b4.w};
    float fx[PPT], f2[PPT], best[PPT];
    int lab[PPT];
#pragma unroll
    for (int u = 0; u < PPT; ++u) {
        fx[u] = (float)(xc + u) * ratiof;
        f2[u] = (((rr[u] * rr[u] + gg[u] * gg[u]) + bb[u] * bb[u]) + fy * fy) + fx[u] * fx[u];
        best[u] = INFINITY;
        lab[u] = 0;
    }
    for (int k = 0; k < K_SEG; ++k) {
        float c0 = cen[k][0], c1 = cen[k][1], c2v = cen[k][2], c3 = cen[k][3], c4 = cen[k][4];
        float c2k = c2l[k];
#pragma unroll
        for (int u = 0; u < PPT; ++u) {
            float dot = rr[u] * c0 + gg[u] * c1 + bb[u] * c2v + fy * c3 + fx[u] * c4;
            float d = (f2[u] + c2k) - 2.0f * dot;
            if (d < best[u]) { best[u] = d; lab[u] = k; }
        }
    }

    if (lab[0] == lab[1] && lab[1] == lab[2] && lab[2] == lab[3]) {
        double* pp = part[lab[0]];
        unsafeAtomicAdd(&pp[0], ((double)rr[0] + (double)rr[1]) + ((double)rr[2] + (double)rr[3]));
        unsafeAtomicAdd(&pp[1], ((double)gg[0] + (double)gg[1]) + ((double)gg[2] + (double)gg[3]));
        unsafeAtomicAdd(&pp[2], ((double)bb[0] + (double)bb[1]) + ((double)bb[2] + (double)bb[3]));
        unsafeAtomicAdd(&pp[3], 4.0 * (double)fy);
        unsafeAtomicAdd(&pp[4], ((double)fx[0] + (double)fx[1]) + ((double)fx[2] + (double)fx[3]));
        unsafeAtomicAdd(&pp[5], 4.0);
    } else {
#pragma unroll
        for (int u = 0; u < PPT; ++u) {
            double* pp = part[lab[u]];
            unsafeAtomicAdd(&pp[0], (double)rr[u]);
            unsafeAtomicAdd(&pp[1], (double)gg[u]);
            unsafeAtomicAdd(&pp[2], (double)bb[u]);
            unsafeAtomicAdd(&pp[3], (double)fy);
            unsafeAtomicAdd(&pp[4], (double)fx[u]);
            unsafeAtomicAdd(&pp[5], 1.0);
        }
    }
    __syncthreads();
    for (int i = t; i < K_SEG * 6; i += TPB) {
        double v = ((double*)part)[i];
        if (v != 0.0) unsafeAtomicAdd(&gsums[b * K_SEG * 6 + i], v);
    }
}

__global__ void update_kernel(double* __restrict__ gsums, float* __restrict__ centers,
                              float* __restrict__ c2s) {
    int b = blockIdx.x;
    int t = threadIdx.x;
    if (t < K_SEG) {
        double* s = gsums + (b * K_SEG + t) * 6;
        double cnt = s[5];
        double denom = cnt > 1.0 ? cnt : 1.0;
        float c[5];
#pragma unroll
        for (int j = 0; j < 5; ++j) { c[j] = (float)(s[j] / denom); s[j] = 0.0; }
        s[5] = 0.0;
        float* cd = centers + (b * K_SEG + t) * 5;
#pragma unroll
        for (int j = 0; j < 5; ++j) cd[j] = c[j];
        c2s[b * K_SEG + t] = (((c[0] * c[0] + c[1] * c[1]) + c[2] * c[2]) + c[3] * c[3]) + c[4] * c[4];
    }
}

__global__ void finalize_kernel(const double* __restrict__ gsums, float* __restrict__ out) {
    int t = threadIdx.x;
    if (t < BATCH) {
        double sr = 0.0, sg = 0.0, sb = 0.0;
        for (int k = 0; k < K_SEG; ++k) {
            const double* s = gsums + (t * K_SEG + k) * 6;
            double cnt = s[5];
            float cntf = (float)(cnt > 1.0 ? cnt : 1.0);
            float wf = 1.0f / cntf;  // fp32 rounding like reference w
            sr += s[0] * (double)wf;
            sg += s[1] * (double)wf;
            sb += s[2] * (double)wf;
        }
        double mr = sr / (double)NPIX, mg = sg / (double)NPIX, mb = sb / (double)NPIX;
        double Drg = (mr - mg) * (mr - mg);
        double Drb = (mr - mb) * (mr - mb);
        double Dgb = (mb - mg) * (mb - mg);
        out[t] = (float)sqrt(Drg * Drg + Drb * Drb + Dgb * Dgb);
    }
}

extern "C" void kernel_launch(void* const* d_in, const int* in_sizes, int n_in,
                              void* d_out, int out_size, void* d_ws, size_t ws_size,
                              hipStream_t stream) {
    const float* x = (const float*)d_in[0];
    float* out = (float*)d_out;
    char* ws = (char*)d_ws;
    double* gsums = (double*)ws;
    float* centers = (float*)(ws + (size_t)BATCH * K_SEG * 6 * 8);
    float* c2s = (float*)(ws + (size_t)BATCH * K_SEG * 6 * 8 + (size_t)BATCH * K_SEG * 5 * 4);

    double S = sqrt((double)NPIX / (double)K_SEG);
    float ratiof = (float)(10.0 / S);

    init_kernel<<<BATCH, 64, 0, stream>>>(x, gsums, centers, c2s, ratiof);

    dim3 agrid(NPIX / (TPB * PPT), BATCH);
    for (int it = 0; it < ITERS; ++it) {
        assign_kernel<<<agrid, TPB, 0, stream>>>(x, gsums, centers, c2s, ratiof);
        update_kernel<<<BATCH, 64, 0, stream>>>(gsums, centers, c2s);
    }
    // 11th assign doubles as final count + per-segment rgb-sum pass
    assign_kernel<<<agrid, TPB, 0, stream>>>(x, gsums, centers, c2s, ratiof);
    finalize_kernel<<<1, 64, 0, stream>>>(gsums, out);
}

// Round 2
// 314.436 us; speedup vs baseline: 3.1766x; 3.1766x over previous
//
#include <hip/hip_runtime.h>
#include <cmath>

#define K_SEG 50
#define ITERS 10
#define H_IMG 512
#define W_IMG 512
#define NPIX (H_IMG * W_IMG)
#define BATCH 16
#define TILE_H 32
#define TILE_W 64
#define TPB 128   // 4 threads/row (16 px each) x 32 rows

// ws layout:
//   gsums  : double[BATCH][K_SEG][6]   (r,g,b,fy,fx,count)   offset 0        (38400 B)
//   centers: float [BATCH][K_SEG][5]                          offset 38400    (16000 B)
//   c2s    : float [BATCH][K_SEG]                             offset 54400    (3200 B)

__global__ void init_kernel(const float* __restrict__ x, double* __restrict__ gsums,
                            float* __restrict__ centers, float* __restrict__ c2s,
                            float ratiof) {
    int b = blockIdx.x;
    int t = threadIdx.x;
    for (int i = t; i < K_SEG * 6; i += blockDim.x) gsums[b * K_SEG * 6 + i] = 0.0;
    if (t < K_SEG) {
        int i = t >> 3, j = t & 7;
        int y = 32 + 64 * i, xc = 32 + 64 * j;  // cy=(i+0.5)*512/8, cx likewise
        const float* xb = x + (size_t)b * 3 * NPIX;
        int p = y * W_IMG + xc;
        float r = xb[p], g = xb[NPIX + p], bl = xb[2 * NPIX + p];
        float fy = (float)y * ratiof, fx = (float)xc * ratiof;
        float* c = centers + (b * K_SEG + t) * 5;
        c[0] = r; c[1] = g; c[2] = bl; c[3] = fy; c[4] = fx;
        c2s[b * K_SEG + t] = (((r * r + g * g) + bl * bl) + fy * fy) + fx * fx;
    }
}

__global__ void __launch_bounds__(TPB, 4) assign_kernel(
        const float* __restrict__ x, double* __restrict__ gsums,
        const float* __restrict__ centers, const float* __restrict__ c2s,
        float ratiof) {
    __shared__ float cen[K_SEG][5];
    __shared__ float c2l[K_SEG];
    __shared__ double part[K_SEG][6];
    __shared__ int klist[K_SEG];
    __shared__ int ncand_s;

    int t = threadIdx.x;
    int tx = blockIdx.x, ty = blockIdx.y, b = blockIdx.z;

    const float* csrc = centers + b * K_SEG * 5;
    for (int i = t; i < K_SEG * 5; i += TPB) ((float*)cen)[i] = csrc[i];
    for (int i = t; i < K_SEG; i += TPB) c2l[i] = c2s[b * K_SEG + i];
    for (int i = t; i < K_SEG * 6; i += TPB) ((double*)part)[i] = 0.0;
    __syncthreads();

    // ---- exact spatial pruning: candidate centers for this tile (wave 0) ----
    if (t < 64) {
        int k = t;
        float R = INFINITY, val = INFINITY;
        if (k < K_SEG) {
            float cy = cen[k][3], cx = cen[k][4];
            float y0 = (float)(ty * TILE_H) * ratiof;
            float y1 = (float)(ty * TILE_H + TILE_H - 1) * ratiof;
            float x0 = (float)(tx * TILE_W) * ratiof;
            float x1 = (float)(tx * TILE_W + TILE_W - 1) * ratiof;
            float dyn = fmaxf(fmaxf(y0 - cy, cy - y1), 0.0f);
            float dxn = fmaxf(fmaxf(x0 - cx, cx - x1), 0.0f);
            float dyf = fmaxf(cy - y0, y1 - cy);
            float dxf = fmaxf(cx - x0, x1 - cx);
            R = dyn * dyn + dxn * dxn;
            // max color-dist^2 is exactly 3 (colors & their means stay in [0,1])
            val = (dyf * dyf + dxf * dxf) + 3.0f;
        }
        float u = val;
        for (int off = 32; off; off >>= 1) u = fminf(u, __shfl_xor(u, off));
        // margin 4.0 >> fp32 expanded-distance rounding (~0.02): prune is exact
        bool cand = (k < K_SEG) && (R <= u + 4.0f);
        unsigned long long m = __ballot(cand);
        if (cand) {
            int pos = __popcll(m & ((1ull << t) - 1ull));
            klist[pos] = k;  // ascending k order preserved -> argmin tie rule kept
        }
        if (t == 0) ncand_s = __popcll(m);
    }
    __syncthreads();
    int ncand = ncand_s;

    // ---- per-thread: 16 consecutive px in one row, in 2 halves of 8 ----
    int row = t >> 2;
    int colq = (t & 3) << 4;
    int gy = ty * TILE_H + row;
    int gx0 = tx * TILE_W + colq;
    const float* xb = x + (size_t)b * 3 * NPIX;
    float fy = (float)gy * ratiof;

    int runlab = -1;
    float sr = 0.0f, sg = 0.0f, sb = 0.0f, sfx = 0.0f;
    int rn = 0;

    for (int h = 0; h < 2; ++h) {
        int gx = gx0 + h * 8;
        size_t p = (size_t)gy * W_IMG + gx;
        float4 ra = *(const float4*)(xb + p);
        float4 rb4 = *(const float4*)(xb + p + 4);
        float4 ga = *(const float4*)(xb + NPIX + p);
        float4 gb4 = *(const float4*)(xb + NPIX + p + 4);
        float4 ba = *(const float4*)(xb + 2 * NPIX + p);
        float4 bb4 = *(const float4*)(xb + 2 * NPIX + p + 4);
        float rr[8] = {ra.x, ra.y, ra.z, ra.w, rb4.x, rb4.y, rb4.z, rb4.w};
        float gg[8] = {ga.x, ga.y, ga.z, ga.w, gb4.x, gb4.y, gb4.z, gb4.w};
        float bv[8] = {ba.x, ba.y, ba.z, ba.w, bb4.x, bb4.y, bb4.z, bb4.w};
        float fx8[8], f28[8], best8[8];
        int lab8[8];
#pragma unroll
        for (int u2 = 0; u2 < 8; ++u2) {
            fx8[u2] = (float)(gx + u2) * ratiof;
            f28[u2] = (((rr[u2] * rr[u2] + gg[u2] * gg[u2]) + bv[u2] * bv[u2]) + fy * fy) + fx8[u2] * fx8[u2];
            best8[u2] = INFINITY;
            lab8[u2] = 0;
        }
        for (int c = 0; c < ncand; ++c) {
            int k = klist[c];
            float c0 = cen[k][0], c1 = cen[k][1], c2v = cen[k][2], c3 = cen[k][3], c4 = cen[k][4];
            float c2k = c2l[k];
#pragma unroll
            for (int u2 = 0; u2 < 8; ++u2) {
                float dot = rr[u2] * c0 + gg[u2] * c1 + bv[u2] * c2v + fy * c3 + fx8[u2] * c4;
                float d = (f28[u2] + c2k) - 2.0f * dot;
                if (d < best8[u2]) { best8[u2] = d; lab8[u2] = k; }
            }
        }
        // run-length aggregate then atomic per run
#pragma unroll
        for (int u2 = 0; u2 < 8; ++u2) {
            if (lab8[u2] != runlab) {
                if (rn > 0) {
                    double* pp = part[runlab];
                    unsafeAtomicAdd(&pp[0], (double)sr);
                    unsafeAtomicAdd(&pp[1], (double)sg);
                    unsafeAtomicAdd(&pp[2], (double)sb);
                    unsafeAtomicAdd(&pp[3], (double)fy * (double)rn);
                    unsafeAtomicAdd(&pp[4], (double)sfx);
                    unsafeAtomicAdd(&pp[5], (double)rn);
                }
                runlab = lab8[u2];
                sr = rr[u2]; sg = gg[u2]; sb = bv[u2]; sfx = fx8[u2]; rn = 1;
            } else {
                sr += rr[u2]; sg += gg[u2]; sb += bv[u2]; sfx += fx8[u2]; rn += 1;
            }
        }
    }
    if (rn > 0) {
        double* pp = part[runlab];
        unsafeAtomicAdd(&pp[0], (double)sr);
        unsafeAtomicAdd(&pp[1], (double)sg);
        unsafeAtomicAdd(&pp[2], (double)sb);
        unsafeAtomicAdd(&pp[3], (double)fy * (double)rn);
        unsafeAtomicAdd(&pp[4], (double)sfx);
        unsafeAtomicAdd(&pp[5], (double)rn);
    }
    __syncthreads();
    for (int i = t; i < K_SEG * 6; i += TPB) {
        double v = ((double*)part)[i];
        if (v != 0.0) unsafeAtomicAdd(&gsums[b * K_SEG * 6 + i], v);
    }
}

__global__ void update_kernel(double* __restrict__ gsums, float* __restrict__ centers,
                              float* __restrict__ c2s) {
    int b = blockIdx.x;
    int t = threadIdx.x;
    if (t < K_SEG) {
        double* s = gsums + (b * K_SEG + t) * 6;
        double cnt = s[5];
        double denom = cnt > 1.0 ? cnt : 1.0;
        float c[5];
#pragma unroll
        for (int j = 0; j < 5; ++j) { c[j] = (float)(s[j] / denom); s[j] = 0.0; }
        s[5] = 0.0;
        float* cd = centers + (b * K_SEG + t) * 5;
#pragma unroll
        for (int j = 0; j < 5; ++j) cd[j] = c[j];
        c2s[b * K_SEG + t] = (((c[0] * c[0] + c[1] * c[1]) + c[2] * c[2]) + c[3] * c[3]) + c[4] * c[4];
    }
}

__global__ void finalize_kernel(const double* __restrict__ gsums, float* __restrict__ out) {
    int t = threadIdx.x;
    if (t < BATCH) {
        double sr = 0.0, sg = 0.0, sb = 0.0;
        for (int k = 0; k < K_SEG; ++k) {
            const double* s = gsums + (t * K_SEG + k) * 6;
            double cnt = s[5];
            float cntf = (float)(cnt > 1.0 ? cnt : 1.0);
            float wf = 1.0f / cntf;  // fp32 rounding like reference w
            sr += s[0] * (double)wf;
            sg += s[1] * (double)wf;
            sb += s[2] * (double)wf;
        }
        double mr = sr / (double)NPIX, mg = sg / (double)NPIX, mb = sb / (double)NPIX;
        double Drg = (mr - mg) * (mr - mg);
        double Drb = (mr - mb) * (mr - mb);
        double Dgb = (mb - mg) * (mb - mg);
        out[t] = (float)sqrt(Drg * Drg + Drb * Drb + Dgb * Dgb);
    }
}

extern "C" void kernel_launch(void* const* d_in, const int* in_sizes, int n_in,
                              void* d_out, int out_size, void* d_ws, size_t ws_size,
                              hipStream_t stream) {
    const float* x = (const float*)d_in[0];
    float* out = (float*)d_out;
    char* ws = (char*)d_ws;
    double* gsums = (double*)ws;
    float* centers = (float*)(ws + (size_t)BATCH * K_SEG * 6 * 8);
    float* c2s = (float*)(ws + (size_t)BATCH * K_SEG * 6 * 8 + (size_t)BATCH * K_SEG * 5 * 4);

    double S = sqrt((double)NPIX / (double)K_SEG);
    float ratiof = (float)(10.0 / S);

    init_kernel<<<BATCH, 64, 0, stream>>>(x, gsums, centers, c2s, ratiof);

    dim3 agrid(W_IMG / TILE_W, H_IMG / TILE_H, BATCH);
    for (int it = 0; it < ITERS; ++it) {
        assign_kernel<<<agrid, TPB, 0, stream>>>(x, gsums, centers, c2s, ratiof);
        update_kernel<<<BATCH, 64, 0, stream>>>(gsums, centers, c2s);
    }
    // 11th assign doubles as final count + per-segment rgb-sum pass
    assign_kernel<<<agrid, TPB, 0, stream>>>(x, gsums, centers, c2s, ratiof);
    finalize_kernel<<<1, 64, 0, stream>>>(gsums, out);
}

// Round 4
// 312.974 us; speedup vs baseline: 3.1914x; 1.0047x over previous
//
#include <hip/hip_runtime.h>
#include <hip/hip_cooperative_groups.h>
#include <cmath>

#define K_SEG 50
#define ITERS 10
#define NPASS (ITERS + 1)       // 10 updates + final labeling pass
#define H_IMG 512
#define W_IMG 512
#define NPIX (H_IMG * W_IMG)
#define BATCH 16
#define TILE 64
#define TPB 256
#define BLK_PER_IMG 64          // 8x8 tiles of 64x64
#define GRID_BLKS (BATCH * BLK_PER_IMG)
#define SLOTS (K_SEG * 6)       // 300 doubles per image

namespace cg = cooperative_groups;

// ===================== fused cooperative path =====================
// ws: g0[BATCH][SLOTS], g1[BATCH][SLOTS]  (2 x 38400 B = 76800 B)

__global__ void zero_ws(double* __restrict__ g) {
    int i = blockIdx.x * 256 + threadIdx.x;
    if (i < 2 * BATCH * SLOTS) g[i] = 0.0;
}

__global__ void __launch_bounds__(TPB, 4) fused_kernel(
        const float* __restrict__ x, double* __restrict__ g0,
        double* __restrict__ g1, float* __restrict__ out, float ratiof) {
    __shared__ float cen[K_SEG][5];
    __shared__ float c2l[K_SEG];
    __shared__ double part[K_SEG][6];
    __shared__ int klist[K_SEG];
    __shared__ int ncand_s;

    int t = threadIdx.x;
    int blk = blockIdx.x;
    int b = blk >> 6;
    int tid6 = blk & 63;
    int ty = tid6 >> 3, tx = tid6 & 7;
    const float* xb = x + (size_t)b * 3 * NPIX;

    int row = t >> 2;
    int colq = (t & 3) << 4;
    int gy = ty * TILE + row;
    int gx0 = tx * TILE + colq;
    float fy = (float)gy * ratiof;

    // colors resident in registers for all 11 passes (48 VGPRs)
    float rr[16], gg[16], bv[16];
    {
        size_t p = (size_t)gy * W_IMG + gx0;
#pragma unroll
        for (int q = 0; q < 4; ++q) {
            float4 r4 = *(const float4*)(xb + p + 4 * q);
            float4 g4 = *(const float4*)(xb + NPIX + p + 4 * q);
            float4 b4 = *(const float4*)(xb + 2 * NPIX + p + 4 * q);
            rr[4*q+0]=r4.x; rr[4*q+1]=r4.y; rr[4*q+2]=r4.z; rr[4*q+3]=r4.w;
            gg[4*q+0]=g4.x; gg[4*q+1]=g4.y; gg[4*q+2]=g4.z; gg[4*q+3]=g4.w;
            bv[4*q+0]=b4.x; bv[4*q+1]=b4.y; bv[4*q+2]=b4.z; bv[4*q+3]=b4.w;
        }
    }

    // this block's LDS partial from 2 passes ago, per parity (delta-flush)
    double prevE0 = 0.0, prevE1 = 0.0, prevO0 = 0.0, prevO1 = 0.0;

    cg::grid_group grid = cg::this_grid();

    for (int it = 0; it < NPASS; ++it) {
        // ---- centers for this pass (identical fp32 math in every block) ----
        if (it == 0) {
            if (t < K_SEG) {
                int i = t >> 3, j = t & 7;
                int y = 32 + 64 * i, xc = 32 + 64 * j;
                int p = y * W_IMG + xc;
                float r = xb[p], g = xb[NPIX + p], bl = xb[2 * NPIX + p];
                float cfy = (float)y * ratiof, cfx = (float)xc * ratiof;
                cen[t][0]=r; cen[t][1]=g; cen[t][2]=bl; cen[t][3]=cfy; cen[t][4]=cfx;
                c2l[t] = (((r*r + g*g) + bl*bl) + cfy*cfy) + cfx*cfx;
            }
        } else {
            const double* gp = (((it - 1) & 1) ? g1 : g0) + (size_t)b * SLOTS;
            for (int i = t; i < SLOTS; i += TPB) ((double*)part)[i] = gp[i];
            __syncthreads();
            if (t < K_SEG) {
                double cnt = part[t][5];
                double denom = cnt > 1.0 ? cnt : 1.0;
                float c0 = (float)(part[t][0] / denom);
                float c1 = (float)(part[t][1] / denom);
                float c2v = (float)(part[t][2] / denom);
                float c3 = (float)(part[t][3] / denom);
                float c4 = (float)(part[t][4] / denom);
                cen[t][0]=c0; cen[t][1]=c1; cen[t][2]=c2v; cen[t][3]=c3; cen[t][4]=c4;
                c2l[t] = (((c0*c0 + c1*c1) + c2v*c2v) + c3*c3) + c4*c4;
            }
        }
        __syncthreads();

        // ---- exact spatial pruning (wave 0) + zero part (all threads) ----
        if (t < 64) {
            int k = t;
            float R = INFINITY, val = INFINITY;
            if (k < K_SEG) {
                float cy = cen[k][3], cx = cen[k][4];
                float y0 = (float)(ty * TILE) * ratiof;
                float y1 = (float)(ty * TILE + TILE - 1) * ratiof;
                float x0 = (float)(tx * TILE) * ratiof;
                float x1 = (float)(tx * TILE + TILE - 1) * ratiof;
                float dyn = fmaxf(fmaxf(y0 - cy, cy - y1), 0.0f);
                float dxn = fmaxf(fmaxf(x0 - cx, cx - x1), 0.0f);
                float dyf = fmaxf(cy - y0, y1 - cy);
                float dxf = fmaxf(cx - x0, x1 - cx);
                R = dyn * dyn + dxn * dxn;
                val = (dyf * dyf + dxf * dxf) + 3.0f;  // color-dist^2 <= 3 exactly
            }
            float u = val;
            for (int off = 32; off; off >>= 1) u = fminf(u, __shfl_xor(u, off));
            bool cand = (k < K_SEG) && (R <= u + 4.0f);  // margin >> fp32 rounding
            unsigned long long m = __ballot(cand);
            if (cand) {
                int pos = __popcll(m & ((1ull << t) - 1ull));
                klist[pos] = k;  // ascending k preserved -> argmin tie rule kept
            }
            if (t == 0) ncand_s = __popcll(m);
        }
        for (int i = t; i < SLOTS; i += TPB) ((double*)part)[i] = 0.0;
        __syncthreads();
        int ncand = ncand_s;

        // ---- labels + run-length aggregation + LDS fp64 atomics ----
        int runlab = -1;
        float sr = 0.0f, sg = 0.0f, sb = 0.0f, sfx = 0.0f;
        int rn = 0;
#pragma unroll
        for (int h = 0; h < 2; ++h) {
            int gx = gx0 + h * 8;
            float fx8[8], f28[8], best8[8];
            int lab8[8];
#pragma unroll
            for (int u = 0; u < 8; ++u) {
                int px = h * 8 + u;
                fx8[u] = (float)(gx + u) * ratiof;
                f28[u] = (((rr[px]*rr[px] + gg[px]*gg[px]) + bv[px]*bv[px]) + fy*fy) + fx8[u]*fx8[u];
                best8[u] = INFINITY;
                lab8[u] = 0;
            }
            for (int c = 0; c < ncand; ++c) {
                int k = klist[c];
                float c0 = cen[k][0], c1 = cen[k][1], c2v = cen[k][2], c3 = cen[k][3], c4 = cen[k][4];
                float c2k = c2l[k];
#pragma unroll
                for (int u = 0; u < 8; ++u) {
                    int px = h * 8 + u;
                    float dot = rr[px]*c0 + gg[px]*c1 + bv[px]*c2v + fy*c3 + fx8[u]*c4;
                    float d = (f28[u] + c2k) - 2.0f * dot;
                    if (d < best8[u]) { best8[u] = d; lab8[u] = k; }
                }
            }
#pragma unroll
            for (int u = 0; u < 8; ++u) {
                int px = h * 8 + u;
                if (lab8[u] != runlab) {
                    if (rn > 0) {
                        double* pp = part[runlab];
                        unsafeAtomicAdd(&pp[0], (double)sr);
                        unsafeAtomicAdd(&pp[1], (double)sg);
                        unsafeAtomicAdd(&pp[2], (double)sb);
                        unsafeAtomicAdd(&pp[3], (double)fy * (double)rn);
                        unsafeAtomicAdd(&pp[4], (double)sfx);
                        unsafeAtomicAdd(&pp[5], (double)rn);
                    }
                    runlab = lab8[u];
                    sr = rr[px]; sg = gg[px]; sb = bv[px]; sfx = fx8[u]; rn = 1;
                } else {
                    sr += rr[px]; sg += gg[px]; sb += bv[px]; sfx += fx8[u]; rn += 1;
                }
            }
        }
        if (rn > 0) {
            double* pp = part[runlab];
            unsafeAtomicAdd(&pp[0], (double)sr);
            unsafeAtomicAdd(&pp[1], (double)sg);
            unsafeAtomicAdd(&pp[2], (double)sb);
            unsafeAtomicAdd(&pp[3], (double)fy * (double)rn);
            unsafeAtomicAdd(&pp[4], (double)sfx);
            unsafeAtomicAdd(&pp[5], (double)rn);
        }
        __syncthreads();

        // ---- parity-delta flush: buf[it&1] (= totals of pass it-2) -> pass it ----
        {
            double* gp = ((it & 1) ? g1 : g0) + (size_t)b * SLOTS;
            if (it & 1) {
                double v0 = ((double*)part)[t];
                double d0 = v0 - prevO0;
                prevO0 = v0;
                if (d0 != 0.0) unsafeAtomicAdd(&gp[t], d0);
                if (t + TPB < SLOTS) {
                    double v1 = ((double*)part)[t + TPB];
                    double d1 = v1 - prevO1;
                    prevO1 = v1;
                    if (d1 != 0.0) unsafeAtomicAdd(&gp[t + TPB], d1);
                }
            } else {
                double v0 = ((double*)part)[t];
                double d0 = v0 - prevE0;
                prevE0 = v0;
                if (d0 != 0.0) unsafeAtomicAdd(&gp[t], d0);
                if (t + TPB < SLOTS) {
                    double v1 = ((double*)part)[t + TPB];
                    double d1 = v1 - prevE1;
                    prevE1 = v1;
                    if (d1 != 0.0) unsafeAtomicAdd(&gp[t + TPB], d1);
                }
            }
        }
        grid.sync();
    }

    // ---- finalize (pass ITERS has even parity -> totals in g0) ----
    if (blk == 0 && t < BATCH) {
        const double* gp = g0 + (size_t)t * SLOTS;
        double sr = 0.0, sg = 0.0, sb = 0.0;
        for (int k = 0; k < K_SEG; ++k) {
            const double* s = gp + k * 6;
            double cnt = s[5];
            float cntf = (float)(cnt > 1.0 ? cnt : 1.0);
            float wf = 1.0f / cntf;  // fp32 rounding like reference w
            sr += s[0] * (double)wf;
            sg += s[1] * (double)wf;
            sb += s[2] * (double)wf;
        }
        double mr = sr / (double)NPIX, mg = sg / (double)NPIX, mb = sb / (double)NPIX;
        double Drg = (mr - mg) * (mr - mg);
        double Drb = (mr - mb) * (mr - mb);
        double Dgb = (mb - mg) * (mb - mg);
        out[t] = (float)sqrt(Drg * Drg + Drb * Drb + Dgb * Dgb);
    }
}

// ===================== fallback path (proven R2 sequence) =====================
// ws: gsums(38400) + centers(16000) + c2s(3200)

__global__ void init_kernelF(const float* __restrict__ x, double* __restrict__ gsums,
                             float* __restrict__ centers, float* __restrict__ c2s,
                             float ratiof) {
    int b = blockIdx.x;
    int t = threadIdx.x;
    for (int i = t; i < SLOTS; i += blockDim.x) gsums[b * SLOTS + i] = 0.0;
    if (t < K_SEG) {
        int i = t >> 3, j = t & 7;
        int y = 32 + 64 * i, xc = 32 + 64 * j;
        const float* xb = x + (size_t)b * 3 * NPIX;
        int p = y * W_IMG + xc;
        float r = xb[p], g = xb[NPIX + p], bl = xb[2 * NPIX + p];
        float fyc = (float)y * ratiof, fxc = (float)xc * ratiof;
        float* c = centers + (b * K_SEG + t) * 5;
        c[0] = r; c[1] = g; c[2] = bl; c[3] = fyc; c[4] = fxc;
        c2s[b * K_SEG + t] = (((r * r + g * g) + bl * bl) + fyc * fyc) + fxc * fxc;
    }
}

__global__ void __launch_bounds__(128, 4) assign_kernelF(
        const float* __restrict__ x, double* __restrict__ gsums,
        const float* __restrict__ centers, const float* __restrict__ c2s,
        float ratiof) {
    __shared__ float cen[K_SEG][5];
    __shared__ float c2l[K_SEG];
    __shared__ double part[K_SEG][6];
    __shared__ int klist[K_SEG];
    __shared__ int ncand_s;

    int t = threadIdx.x;
    int tx = blockIdx.x, ty = blockIdx.y, b = blockIdx.z;

    const float* csrc = centers + b * K_SEG * 5;
    for (int i = t; i < K_SEG * 5; i += 128) ((float*)cen)[i] = csrc[i];
    for (int i = t; i < K_SEG; i += 128) c2l[i] = c2s[b * K_SEG + i];
    for (int i = t; i < SLOTS; i += 128) ((double*)part)[i] = 0.0;
    __syncthreads();

    if (t < 64) {
        int k = t;
        float R = INFINITY, val = INFINITY;
        if (k < K_SEG) {
            float cy = cen[k][3], cx = cen[k][4];
            float y0 = (float)(ty * 32) * ratiof;
            float y1 = (float)(ty * 32 + 31) * ratiof;
            float x0 = (float)(tx * 64) * ratiof;
            float x1 = (float)(tx * 64 + 63) * ratiof;
            float dyn = fmaxf(fmaxf(y0 - cy, cy - y1), 0.0f);
            float dxn = fmaxf(fmaxf(x0 - cx, cx - x1), 0.0f);
            float dyf = fmaxf(cy - y0, y1 - cy);
            float dxf = fmaxf(cx - x0, x1 - cx);
            R = dyn * dyn + dxn * dxn;
            val = (dyf * dyf + dxf * dxf) + 3.0f;
        }
        float u = val;
        for (int off = 32; off; off >>= 1) u = fminf(u, __shfl_xor(u, off));
        bool cand = (k < K_SEG) && (R <= u + 4.0f);
        unsigned long long m = __ballot(cand);
        if (cand) {
            int pos = __popcll(m & ((1ull << t) - 1ull));
            klist[pos] = k;
        }
        if (t == 0) ncand_s = __popcll(m);
    }
    __syncthreads();
    int ncand = ncand_s;

    int row = t >> 2;
    int colq = (t & 3) << 4;
    int gy = ty * 32 + row;
    int gx0 = tx * 64 + colq;
    const float* xb = x + (size_t)b * 3 * NPIX;
    float fy = (float)gy * ratiof;

    int runlab = -1;
    float sr = 0.0f, sg = 0.0f, sb = 0.0f, sfx = 0.0f;
    int rn = 0;

    for (int h = 0; h < 2; ++h) {
        int gx = gx0 + h * 8;
        size_t p = (size_t)gy * W_IMG + gx;
        float4 ra = *(const float4*)(xb + p);
        float4 rb4 = *(const float4*)(xb + p + 4);
        float4 ga = *(const float4*)(xb + NPIX + p);
        float4 gb4 = *(const float4*)(xb + NPIX + p + 4);
        float4 ba = *(const float4*)(xb + 2 * NPIX + p);
        float4 bb4 = *(const float4*)(xb + 2 * NPIX + p + 4);
        float rr[8] = {ra.x, ra.y, ra.z, ra.w, rb4.x, rb4.y, rb4.z, rb4.w};
        float gg[8] = {ga.x, ga.y, ga.z, ga.w, gb4.x, gb4.y, gb4.z, gb4.w};
        float bv[8] = {ba.x, ba.y, ba.z, ba.w, bb4.x, bb4.y, bb4.z, bb4.w};
        float fx8[8], f28[8], best8[8];
        int lab8[8];
#pragma unroll
        for (int u2 = 0; u2 < 8; ++u2) {
            fx8[u2] = (float)(gx + u2) * ratiof;
            f28[u2] = (((rr[u2] * rr[u2] + gg[u2] * gg[u2]) + bv[u2] * bv[u2]) + fy * fy) + fx8[u2] * fx8[u2];
            best8[u2] = INFINITY;
            lab8[u2] = 0;
        }
        for (int c = 0; c < ncand; ++c) {
            int k = klist[c];
            float c0 = cen[k][0], c1 = cen[k][1], c2v = cen[k][2], c3 = cen[k][3], c4 = cen[k][4];
            float c2k = c2l[k];
#pragma unroll
            for (int u2 = 0; u2 < 8; ++u2) {
                float dot = rr[u2] * c0 + gg[u2] * c1 + bv[u2] * c2v + fy * c3 + fx8[u2] * c4;
                float d = (f28[u2] + c2k) - 2.0f * dot;
                if (d < best8[u2]) { best8[u2] = d; lab8[u2] = k; }
            }
        }
#pragma unroll
        for (int u2 = 0; u2 < 8; ++u2) {
            if (lab8[u2] != runlab) {
                if (rn > 0) {
                    double* pp = part[runlab];
                    unsafeAtomicAdd(&pp[0], (double)sr);
                    unsafeAtomicAdd(&pp[1], (double)sg);
                    unsafeAtomicAdd(&pp[2], (double)sb);
                    unsafeAtomicAdd(&pp[3], (double)fy * (double)rn);
                    unsafeAtomicAdd(&pp[4], (double)sfx);
                    unsafeAtomicAdd(&pp[5], (double)rn);
                }
                runlab = lab8[u2];
                sr = rr[u2]; sg = gg[u2]; sb = bv[u2]; sfx = fx8[u2]; rn = 1;
            } else {
                sr += rr[u2]; sg += gg[u2]; sb += bv[u2]; sfx += fx8[u2]; rn += 1;
            }
        }
    }
    if (rn > 0) {
        double* pp = part[runlab];
        unsafeAtomicAdd(&pp[0], (double)sr);
        unsafeAtomicAdd(&pp[1], (double)sg);
        unsafeAtomicAdd(&pp[2], (double)sb);
        unsafeAtomicAdd(&pp[3], (double)fy * (double)rn);
        unsafeAtomicAdd(&pp[4], (double)sfx);
        unsafeAtomicAdd(&pp[5], (double)rn);
    }
    __syncthreads();
    for (int i = t; i < SLOTS; i += 128) {
        double v = ((double*)part)[i];
        if (v != 0.0) unsafeAtomicAdd(&gsums[b * SLOTS + i], v);
    }
}

__global__ void update_kernelF(double* __restrict__ gsums, float* __restrict__ centers,
                               float* __restrict__ c2s) {
    int b = blockIdx.x;
    int t = threadIdx.x;
    if (t < K_SEG) {
        double* s = gsums + (b * K_SEG + t) * 6;
        double cnt = s[5];
        double denom = cnt > 1.0 ? cnt : 1.0;
        float c[5];
#pragma unroll
        for (int j = 0; j < 5; ++j) { c[j] = (float)(s[j] / denom); s[j] = 0.0; }
        s[5] = 0.0;
        float* cd = centers + (b * K_SEG + t) * 5;
#pragma unroll
        for (int j = 0; j < 5; ++j) cd[j] = c[j];
        c2s[b * K_SEG + t] = (((c[0] * c[0] + c[1] * c[1]) + c[2] * c[2]) + c[3] * c[3]) + c[4] * c[4];
    }
}

__global__ void finalize_kernelF(const double* __restrict__ gsums, float* __restrict__ out) {
    int t = threadIdx.x;
    if (t < BATCH) {
        double sr = 0.0, sg = 0.0, sb = 0.0;
        for (int k = 0; k < K_SEG; ++k) {
            const double* s = gsums + (t * K_SEG + k) * 6;
            double cnt = s[5];
            float cntf = (float)(cnt > 1.0 ? cnt : 1.0);
            float wf = 1.0f / cntf;
            sr += s[0] * (double)wf;
            sg += s[1] * (double)wf;
            sb += s[2] * (double)wf;
        }
        double mr = sr / (double)NPIX, mg = sg / (double)NPIX, mb = sb / (double)NPIX;
        double Drg = (mr - mg) * (mr - mg);
        double Drb = (mr - mb) * (mr - mb);
        double Dgb = (mb - mg) * (mb - mg);
        out[t] = (float)sqrt(Drg * Drg + Drb * Drb + Dgb * Dgb);
    }
}

extern "C" void kernel_launch(void* const* d_in, const int* in_sizes, int n_in,
                              void* d_out, int out_size, void* d_ws, size_t ws_size,
                              hipStream_t stream) {
    const float* x = (const float*)d_in[0];
    float* out = (float*)d_out;
    char* ws = (char*)d_ws;

    double S = sqrt((double)NPIX / (double)K_SEG);
    float ratiof = (float)(10.0 / S);

    // ---- host-side capability gate (pure queries: graph-capture-safe) ----
    int dev = 0;
    (void)hipGetDevice(&dev);
    int ncu = 0, coopOK = 0, occ = 0;
    (void)hipDeviceGetAttribute(&ncu, hipDeviceAttributeMultiprocessorCount, dev);
    (void)hipDeviceGetAttribute(&coopOK, hipDeviceAttributeCooperativeLaunch, dev);
    (void)hipOccupancyMaxActiveBlocksPerMultiprocessor(&occ, fused_kernel, TPB, 0);

    if (coopOK && (size_t)occ * (size_t)ncu >= GRID_BLKS &&
        ws_size >= (size_t)2 * BATCH * SLOTS * sizeof(double)) {
        double* g0 = (double*)ws;
        double* g1 = g0 + (size_t)BATCH * SLOTS;
        int nzero = 2 * BATCH * SLOTS;
        zero_ws<<<(nzero + 255) / 256, 256, 0, stream>>>(g0);
        void* args[] = {(void*)&x, (void*)&g0, (void*)&g1, (void*)&out, (void*)&ratiof};
        hipError_t e = hipLaunchCooperativeKernel(fused_kernel, dim3(GRID_BLKS), dim3(TPB),
                                                  args, 0, stream);
        if (e == hipSuccess) return;
        (void)hipGetLastError();  // clear and fall through to proven path
    }

    // ---- fallback: R2's passing 314us sequence ----
    double* gsums = (double*)ws;
    float* centers = (float*)(ws + (size_t)BATCH * SLOTS * 8);
    float* c2s = (float*)(ws + (size_t)BATCH * SLOTS * 8 + (size_t)BATCH * K_SEG * 5 * 4);

    init_kernelF<<<BATCH, 64, 0, stream>>>(x, gsums, centers, c2s, ratiof);
    dim3 agrid(W_IMG / 64, H_IMG / 32, BATCH);
    for (int it = 0; it < ITERS; ++it) {
        assign_kernelF<<<agrid, 128, 0, stream>>>(x, gsums, centers, c2s, ratiof);
        update_kernelF<<<BATCH, 64, 0, stream>>>(gsums, centers, c2s);
    }
    assign_kernelF<<<agrid, 128, 0, stream>>>(x, gsums, centers, c2s, ratiof);
    finalize_kernelF<<<1, 64, 0, stream>>>(gsums, out);
}